// Round 10
// baseline (20781.441 us; speedup 1.0000x reference)
//
#include <hip/hip_runtime.h>
#include <stdint.h>

// Problem dims
#define B_    64
#define T_    2048
#define IN_   64
#define H_    512
#define H2_   1024
#define OUT_  32
#define KTOT  576          // IN_ + H_

// Grid: 256 blocks = 8 batch-groups x 32 col-groups, 256 threads.
// Each block processes its bg's 8 batches as TWO pipelined 4-batch halves.
#define NBG   8
#define NCG   32
#define NTHR  256
#define KSL   18           // k per slice (32 slices x 18 = 576)
#define RS4   4            // bufA row stride (4 batches per half)

// ws layout (32-bit words)
// Flag slot per (bg, phase, half, cg), each on its own 64B line.
#define FLAG_STRIDE 16
#define FLAG_WORDS  (NBG * 2 * 2 * NCG * FLAG_STRIDE)   // 16384
#define ABORT_IDX   FLAG_WORDS                           // 16384
#define BUF_BASE    (FLAG_WORDS + 64)                    // 16448 (128B-aligned)
#define XSLAB       32768    // words per slab: [8 bg][512 j][8 b]
#define SLOT(bg, ph, h, cg) ((((((bg)*2 + (ph))*2 + (h)) * NCG) + (cg)) * FLAG_STRIDE)

// ---- verified R8 exchange primitives (sc1 = MALL coherence point) ----
__device__ __forceinline__ void pubf(float* p, float v) {
  asm volatile("global_atomic_swap %0, %1, off sc1\n\ts_waitcnt vmcnt(0)"
               :: "v"(p), "v"(v) : "memory");
}
__device__ __forceinline__ unsigned flagld(const unsigned* p) {
  unsigned r;
  asm volatile("global_load_dword %0, %1, off sc0 sc1\n\ts_waitcnt vmcnt(0)"
               : "=v"(r) : "v"(p) : "memory");
  return r;
}
__device__ __forceinline__ void barrier_arrive(unsigned* flags, int slot, unsigned tgt) {
  asm volatile("s_waitcnt vmcnt(0)" ::: "memory");
  __syncthreads();
  if (threadIdx.x == 0) {
    unsigned* p = flags + slot;
    asm volatile("global_atomic_swap %0, %1, off sc1" :: "v"(p), "v"(tgt) : "memory");
  }
}
__device__ __forceinline__ bool barrier_wait(unsigned* flags, int base, unsigned tgt,
                                             unsigned* abort_w, int* s_ok) {
  const int tid = threadIdx.x;
  int ok = 1;
  if (tid < NCG) {   // 32 lanes of wave 0 poll 32 distinct lines in parallel
    const unsigned* f = flags + base + tid * FLAG_STRIDE;
    int polls = 0;
    while (flagld(f) < tgt) {
      __builtin_amdgcn_s_sleep(1);
      if ((++polls & 255) == 0) {
        if (__hip_atomic_load(abort_w, __ATOMIC_RELAXED, __HIP_MEMORY_SCOPE_AGENT) != 0u ||
            polls > 2000000) {
          __hip_atomic_store(abort_w, 1u, __ATOMIC_RELAXED, __HIP_MEMORY_SCOPE_AGENT);
          ok = 0;
          break;
        }
      }
    }
  }
  if (tid < 64) {
    unsigned long long bad = __ballot(ok == 0);
    if (tid == 0) *s_ok = (bad == 0ull) ? 1 : 0;
  }
  __syncthreads();
  __atomic_signal_fence(__ATOMIC_ACQUIRE);
  return *s_ok != 0;
}

__global__ __launch_bounds__(256) void gru_init(float* ws, const float* __restrict__ x0) {
  int i = blockIdx.x * blockDim.x + threadIdx.x;
  int stride = gridDim.x * blockDim.x;
  unsigned* w = (unsigned*)ws;
  for (int k = i; k < BUF_BASE; k += stride) w[k] = 0u;
  for (int k = i; k < NBG * H_ * 8; k += stride) {
    int bg = k >> 12, j = (k >> 3) & (H_ - 1), b = k & 7;
    ws[BUF_BASE + k] = x0[(bg * 8 + b) * H_ + j];
  }
}

// Stage one half's 512-row slab slice (4 floats/row) into LDS buf rows 64..639.
__device__ __forceinline__ void stage_slab(const float* slab, int bg, int h, float* buf) {
  const int tid = threadIdx.x;
  const float* p0 = &slab[(size_t)(bg * H_ + tid) * 8 + 4 * h];
  const float* p1 = &slab[(size_t)(bg * H_ + tid + 256) * 8 + 4 * h];
  float4 a, b;
  asm volatile(
      "global_load_dwordx4 %0, %2, off sc0 sc1\n\t"
      "global_load_dwordx4 %1, %3, off sc0 sc1\n\t"
      "s_waitcnt vmcnt(0)"
      : "=&v"(a), "=&v"(b) : "v"(p0), "v"(p1) : "memory");
  *(float4*)&buf[(64 + tid) * RS4] = a;
  *(float4*)&buf[(64 + tid + 256) * RS4] = b;
}

__device__ __forceinline__ void stage_u(const float* u, int bg, int h, int t, float* buf) {
  const int tid = threadIdx.x;
  if (tid < 128) {
    int k2 = tid & 31, b4 = tid >> 5;
    float2 uv = *(const float2*)&u[((size_t)(bg * 8 + 4 * h + b4) * T_ + t) * IN_ + 2 * k2];
    buf[(2 * k2) * RS4 + b4] = uv.x;
    buf[(2 * k2 + 1) * RS4 + b4] = uv.y;
  }
}

__device__ __forceinline__ void compute_A(const float* buf, const float wA[KSL][4],
                                          float* pA, int kb, int g, int w, int cq) {
  float acc[4][4] = {};
#pragma unroll
  for (int i = 0; i < KSL; ++i) {
    float4 xv = *(const float4*)&buf[(kb + i) * RS4];
#pragma unroll
    for (int m = 0; m < 4; ++m) {
      float wv = wA[i][m];
      acc[m][0] += wv * xv.x; acc[m][1] += wv * xv.y;
      acc[m][2] += wv * xv.z; acc[m][3] += wv * xv.w;
    }
  }
#pragma unroll
  for (int m = 0; m < 4; ++m)
#pragma unroll
    for (int b = 0; b < 4; ++b) {
      acc[m][b] += __shfl_xor(acc[m][b], 8);
      acc[m][b] += __shfl_xor(acc[m][b], 16);
      acc[m][b] += __shfl_xor(acc[m][b], 32);
    }
  if (g == 0) {
#pragma unroll
    for (int m = 0; m < 4; ++m)
      *(float4*)&pA[(w * 32 + 4 * cq + m) * RS4] =
          make_float4(acc[m][0], acc[m][1], acc[m][2], acc[m][3]);
  }
}

__device__ __forceinline__ void compute_B(const float* buf, const float wB[KSL][2],
                                          float* pB, int kb, int g, int w, int cq) {
  float acc[2][4] = {};
#pragma unroll
  for (int i = 0; i < KSL; ++i) {
    float4 xv = *(const float4*)&buf[(kb + i) * RS4];
#pragma unroll
    for (int m = 0; m < 2; ++m) {
      float wv = wB[i][m];
      acc[m][0] += wv * xv.x; acc[m][1] += wv * xv.y;
      acc[m][2] += wv * xv.z; acc[m][3] += wv * xv.w;
    }
  }
#pragma unroll
  for (int m = 0; m < 2; ++m)
#pragma unroll
    for (int b = 0; b < 4; ++b) {
      acc[m][b] += __shfl_xor(acc[m][b], 8);
      acc[m][b] += __shfl_xor(acc[m][b], 16);
      acc[m][b] += __shfl_xor(acc[m][b], 32);
    }
  if (g == 0) {
#pragma unroll
    for (int m = 0; m < 2; ++m)
      *(float4*)&pB[(w * 16 + 2 * cq + m) * RS4] =
          make_float4(acc[m][0], acc[m][1], acc[m][2], acc[m][3]);
  }
}

__device__ __forceinline__ void do_y(const float* buf, const float wy[16], float by,
                                     float* out, int bg, int h, int t, int cg) {
  const int tid = threadIdx.x;
  if (tid < 128) {
    int yb4 = tid >> 5, yq = tid & 31;
    float yp = 0.0f;
#pragma unroll
    for (int i = 0; i < 16; ++i)
      yp += wy[i] * buf[(64 + yq + 32 * i) * RS4 + yb4];
    yp += __shfl_xor(yp, 1);  yp += __shfl_xor(yp, 2);
    yp += __shfl_xor(yp, 4);  yp += __shfl_xor(yp, 8);
    yp += __shfl_xor(yp, 16);
    if (yq == 0)
      out[((size_t)(bg * 8 + 4 * h + yb4) * T_ + t) * OUT_ + cg] = yp + by;
  }
}

__global__ __launch_bounds__(NTHR, 1) void gru_main(
    const float* __restrict__ u, const float* __restrict__ kfz,
    const float* __restrict__ bfz, const float* __restrict__ kr,
    const float* __restrict__ br, const float* __restrict__ wout,
    const float* __restrict__ bout, float* __restrict__ out, float* ws) {
  unsigned* flags = (unsigned*)ws;
  unsigned* abort_w = flags + ABORT_IDX;
  float* xg0 = ws + BUF_BASE;
  float* xg1 = xg0 + XSLAB;
  float* xfg = xg1 + XSLAB;

  const int bg  = blockIdx.x & 7;
  const int cg  = blockIdx.x >> 3;
  const int tid = threadIdx.x;
  const int w   = tid >> 6;
  const int l   = tid & 63;
  const int cq  = l & 7;
  const int g   = l >> 3;
  const int kb  = (w * 8 + g) * KSL;

  __shared__ float buf0[KTOT * RS4];   // half 0: u | x or f*x (4 batches)
  __shared__ float buf1[KTOT * RS4];   // half 1
  __shared__ float pA[4 * 32 * RS4];
  __shared__ float pB[4 * 16 * RS4];
  __shared__ float rbuf[16 * 4];
  __shared__ int s_ok;

  // ---- one-time: weights into registers (shared by both halves) ----
  float wA[KSL][4];
#pragma unroll
  for (int i = 0; i < KSL; ++i)
#pragma unroll
    for (int m = 0; m < 4; ++m) {
      int c = 4 * cq + m;
      int gcol = (c < 16) ? (16 * cg + c) : (512 + 16 * cg + (c - 16));
      wA[i][m] = kfz[(size_t)(kb + i) * H2_ + gcol];
    }
  float wB[KSL][2];
#pragma unroll
  for (int i = 0; i < KSL; ++i)
#pragma unroll
    for (int m = 0; m < 2; ++m)
      wB[i][m] = kr[(size_t)(kb + i) * H_ + (16 * cg + 2 * cq + m)];
  float wy[16];
  {
    int yq = tid & 31;
#pragma unroll
    for (int i = 0; i < 16; ++i) wy[i] = wout[cg * H_ + (yq + 32 * i)];
  }
  const float by = bout[cg];
  float biasA = 0.0f, biasB = 0.0f;
  if (tid < 128) {
    int fc = tid >> 2;
    int fzc = (fc < 16) ? (16 * cg + fc) : (512 + 16 * cg + (fc - 16));
    biasA = bfz[fzc];
  }
  if (tid < 64) biasB = br[16 * cg + (tid >> 2)];

  const int slotA0 = SLOT(bg, 0, 0, cg), baseA0 = SLOT(bg, 0, 0, 0);
  const int slotA1 = SLOT(bg, 0, 1, cg), baseA1 = SLOT(bg, 0, 1, 0);
  const int slotB0 = SLOT(bg, 1, 0, cg), baseB0 = SLOT(bg, 1, 0, 0);
  const int slotB1 = SLOT(bg, 1, 1, cg), baseB1 = SLOT(bg, 1, 1, 0);

  float zr0 = 0.0f, xo0 = 0.0f, zr1 = 0.0f, xo1 = 0.0f;

  for (int t = 0; t < T_; ++t) {
    float* xcur = (t & 1) ? xg1 : xg0;
    float* xnxt = (t & 1) ? xg0 : xg1;
    const unsigned tp1 = (unsigned)(t + 1);

    // ================== half 0, phase A ==================
    stage_slab(xcur, bg, 0, buf0);        // B(h0,t-1) waited at end of prev iter
    stage_u(u, bg, 0, t, buf0);
    __syncthreads();
    compute_A(buf0, wA, pA, kb, g, w, cq);
    __syncthreads();
    if (tid < 128) {                      // finalize A h0
      int fc = tid >> 2, fb = tid & 3;
      float s = pA[(0 * 32 + fc) * RS4 + fb] + pA[(1 * 32 + fc) * RS4 + fb] +
                pA[(2 * 32 + fc) * RS4 + fb] + pA[(3 * 32 + fc) * RS4 + fb] + biasA;
      float sig = 1.0f / (1.0f + __expf(-s));
      if (fc < 16) {
        float xo = buf0[(64 + 16 * cg + fc) * RS4 + fb];
        pubf(&xfg[(size_t)(bg * H_ + 16 * cg + fc) * 8 + 0 + fb], sig * xo);
      } else {
        zr0 = sig;
        xo0 = buf0[(64 + 16 * cg + (fc - 16)) * RS4 + fb];
      }
    }
    barrier_arrive(flags, slotA0, tp1);

    // ================== half 1, phase A (fills A0's flight window) ======
    if (!barrier_wait(flags, baseB1, (unsigned)t, abort_w, &s_ok)) return;
    stage_slab(xcur, bg, 1, buf1);
    stage_u(u, bg, 1, t, buf1);
    __syncthreads();
    do_y(buf0, wy, by, out, bg, 0, t, cg);   // y h0 (buf0 still holds x)
    compute_A(buf1, wA, pA, kb, g, w, cq);
    __syncthreads();
    if (tid < 128) {                      // finalize A h1
      int fc = tid >> 2, fb = tid & 3;
      float s = pA[(0 * 32 + fc) * RS4 + fb] + pA[(1 * 32 + fc) * RS4 + fb] +
                pA[(2 * 32 + fc) * RS4 + fb] + pA[(3 * 32 + fc) * RS4 + fb] + biasA;
      float sig = 1.0f / (1.0f + __expf(-s));
      if (fc < 16) {
        float xo = buf1[(64 + 16 * cg + fc) * RS4 + fb];
        pubf(&xfg[(size_t)(bg * H_ + 16 * cg + fc) * 8 + 4 + fb], sig * xo);
      } else {
        zr1 = sig;
        xo1 = buf1[(64 + 16 * cg + (fc - 16)) * RS4 + fb];
      }
    }
    barrier_arrive(flags, slotA1, tp1);

    // ================== half 0, phase B ==================
    if (!barrier_wait(flags, baseA0, tp1, abort_w, &s_ok)) return;
    stage_slab(xfg, bg, 0, buf0);         // f*x h0 (u rows intact)
    __syncthreads();
    do_y(buf1, wy, by, out, bg, 1, t, cg);   // y h1 (buf1 still holds x)
    compute_B(buf0, wB, pB, kb, g, w, cq);
    __syncthreads();
    if (tid < 64) {
      int fcB = tid >> 2, fb = tid & 3;
      float s = pB[(0 * 16 + fcB) * RS4 + fb] + pB[(1 * 16 + fcB) * RS4 + fb] +
                pB[(2 * 16 + fcB) * RS4 + fb] + pB[(3 * 16 + fcB) * RS4 + fb] + biasB;
      float e = __expf(2.0f * s);
      rbuf[fcB * 4 + fb] = 1.0f - 2.0f / (1.0f + e);
    }
    __syncthreads();
    if (tid >= 64 && tid < 128) {         // update h0 (threads holding zr0/xo0)
      int fc = tid >> 2, fb = tid & 3;    // fc 16..31
      float r = rbuf[(fc - 16) * 4 + fb];
      float xn = xo0 + zr0 * (r - xo0);
      pubf(&xnxt[(size_t)(bg * H_ + 16 * cg + (fc - 16)) * 8 + 0 + fb], xn);
    }
    barrier_arrive(flags, slotB0, tp1);

    // ================== half 1, phase B ==================
    if (!barrier_wait(flags, baseA1, tp1, abort_w, &s_ok)) return;
    stage_slab(xfg, bg, 1, buf1);
    __syncthreads();
    compute_B(buf1, wB, pB, kb, g, w, cq);
    __syncthreads();
    if (tid < 64) {
      int fcB = tid >> 2, fb = tid & 3;
      float s = pB[(0 * 16 + fcB) * RS4 + fb] + pB[(1 * 16 + fcB) * RS4 + fb] +
                pB[(2 * 16 + fcB) * RS4 + fb] + pB[(3 * 16 + fcB) * RS4 + fb] + biasB;
      float e = __expf(2.0f * s);
      rbuf[fcB * 4 + fb] = 1.0f - 2.0f / (1.0f + e);
    }
    __syncthreads();
    if (tid >= 64 && tid < 128) {         // update h1
      int fc = tid >> 2, fb = tid & 3;
      float r = rbuf[(fc - 16) * 4 + fb];
      float xn = xo1 + zr1 * (r - xo1);
      pubf(&xnxt[(size_t)(bg * H_ + 16 * cg + (fc - 16)) * 8 + 4 + fb], xn);
    }
    barrier_arrive(flags, slotB1, tp1);

    // ---- wait B h0 (its flight hidden behind half-1 B) before next stage ----
    if (!barrier_wait(flags, baseB0, tp1, abort_w, &s_ok)) return;
  }
}

extern "C" void kernel_launch(void* const* d_in, const int* in_sizes, int n_in,
                              void* d_out, int out_size, void* d_ws, size_t ws_size,
                              hipStream_t stream) {
  const float* u    = (const float*)d_in[0];
  const float* x0   = (const float*)d_in[1];
  const float* kfz  = (const float*)d_in[2];
  const float* bfz  = (const float*)d_in[3];
  const float* kr   = (const float*)d_in[4];
  const float* br   = (const float*)d_in[5];
  const float* wout = (const float*)d_in[6];
  const float* bout = (const float*)d_in[7];
  float* out = (float*)d_out;
  float* ws  = (float*)d_ws;

  hipLaunchKernelGGL(gru_init, dim3(64), dim3(256), 0, stream, ws, x0);
  hipLaunchKernelGGL(gru_main, dim3(NBG * NCG), dim3(NTHR), 0, stream,
                     u, kfz, bfz, kr, br, wout, bout, out, ws);
}